// Round 1
// baseline (344.671 us; speedup 1.0000x reference)
//
#include <hip/hip_runtime.h>

#define VQ_EPS 1e-12f

// Kernel 1: normalize codebook rows, store normalized rows + post-normalization
// squared norms (mirrors reference: sum(cb*cb) computed AFTER normalization).
__global__ __launch_bounds__(64) void cb_norm_kernel(const float* __restrict__ cb,
                                                     float* __restrict__ cbn,
                                                     float* __restrict__ knorm2) {
    const int k = blockIdx.x;       // 512 rows
    const int c = threadIdx.x;      // 64 channels
    float v = cb[k * 64 + c];
    float s = v * v;
    #pragma unroll
    for (int off = 32; off > 0; off >>= 1) s += __shfl_xor(s, off, 64);
    float n = sqrtf(s);
    float cn = v / fmaxf(n, VQ_EPS);     // elementwise divide, like F.normalize
    cbn[k * 64 + c] = cn;
    float s2 = cn * cn;
    #pragma unroll
    for (int off = 32; off > 0; off >>= 1) s2 += __shfl_xor(s2, off, 64);
    if (c == 0) knorm2[k] = s2;
}

// Kernel 2: one thread per pixel (b,h,w); lane index = w -> coalesced x loads
// per channel and coalesced codes/indices stores. x kept in 64 VGPRs; codebook
// reads are wave-uniform -> scalar loads from L2-hot 128 KB table.
__global__ __launch_bounds__(256) void vq_kernel(const float* __restrict__ x,
                                                 const float* __restrict__ cbn,
                                                 const float* __restrict__ knorm2,
                                                 float* __restrict__ codes,
                                                 float* __restrict__ idxout) {
    const int p = blockIdx.x * 256 + threadIdx.x;   // 131072 pixels
    const int w = p & 63;
    const int h = (p >> 6) & 63;
    const int b = p >> 12;

    const float* xp = x + ((size_t)b * 64 * 4096) + h * 64 + w;

    float xr[64];
    float ss = 0.0f;
    #pragma unroll
    for (int c = 0; c < 64; ++c) {
        xr[c] = xp[(size_t)c * 4096];
        ss = fmaf(xr[c], xr[c], ss);
    }
    const float inv = 1.0f / fmaxf(sqrtf(ss), VQ_EPS);  // IEEE divide (no fast-math)
    const float m2  = -2.0f * inv;   // score_k = knorm2[k] + m2 * (x_raw . cbn_k)

    float best = 3.0e38f;
    int bestk = 0;

    for (int k0 = 0; k0 < 512; k0 += 4) {
        const float4* c0 = (const float4*)(cbn + (size_t)(k0 + 0) * 64);
        const float4* c1 = (const float4*)(cbn + (size_t)(k0 + 1) * 64);
        const float4* c2 = (const float4*)(cbn + (size_t)(k0 + 2) * 64);
        const float4* c3 = (const float4*)(cbn + (size_t)(k0 + 3) * 64);
        float d0 = 0.0f, d1 = 0.0f, d2 = 0.0f, d3 = 0.0f;
        #pragma unroll
        for (int q = 0; q < 16; ++q) {
            float4 v0 = c0[q];
            float4 v1 = c1[q];
            float4 v2 = c2[q];
            float4 v3 = c3[q];
            const int cc = q * 4;
            d0 = fmaf(xr[cc + 0], v0.x, d0);
            d0 = fmaf(xr[cc + 1], v0.y, d0);
            d0 = fmaf(xr[cc + 2], v0.z, d0);
            d0 = fmaf(xr[cc + 3], v0.w, d0);
            d1 = fmaf(xr[cc + 0], v1.x, d1);
            d1 = fmaf(xr[cc + 1], v1.y, d1);
            d1 = fmaf(xr[cc + 2], v1.z, d1);
            d1 = fmaf(xr[cc + 3], v1.w, d1);
            d2 = fmaf(xr[cc + 0], v2.x, d2);
            d2 = fmaf(xr[cc + 1], v2.y, d2);
            d2 = fmaf(xr[cc + 2], v2.z, d2);
            d2 = fmaf(xr[cc + 3], v2.w, d2);
            d3 = fmaf(xr[cc + 0], v3.x, d3);
            d3 = fmaf(xr[cc + 1], v3.y, d3);
            d3 = fmaf(xr[cc + 2], v3.z, d3);
            d3 = fmaf(xr[cc + 3], v3.w, d3);
        }
        // score = ||cb_k||^2 - 2*inv*(x.cb_k); strict < keeps first-min (numpy tie-break)
        float s0 = fmaf(m2, d0, knorm2[k0 + 0]);
        float s1 = fmaf(m2, d1, knorm2[k0 + 1]);
        float s2 = fmaf(m2, d2, knorm2[k0 + 2]);
        float s3 = fmaf(m2, d3, knorm2[k0 + 3]);
        if (s0 < best) { best = s0; bestk = k0 + 0; }
        if (s1 < best) { best = s1; bestk = k0 + 1; }
        if (s2 < best) { best = s2; bestk = k0 + 2; }
        if (s3 < best) { best = s3; bestk = k0 + 3; }
    }

    // Epilogue: codes[b, :, h, w] = cbn[bestk, :]  (coalesced store per channel,
    // gather reads served by L1/L2 -- cbn is 128 KB hot), indices[b,h,w] = bestk.
    const float* crow = cbn + (size_t)bestk * 64;
    float* cp = codes + ((size_t)b * 64 * 4096) + h * 64 + w;
    #pragma unroll
    for (int c = 0; c < 64; ++c) {
        cp[(size_t)c * 4096] = crow[c];
    }
    idxout[(b * 64 + h) * 64 + w] = (float)bestk;
}

extern "C" void kernel_launch(void* const* d_in, const int* in_sizes, int n_in,
                              void* d_out, int out_size, void* d_ws, size_t ws_size,
                              hipStream_t stream) {
    const float* x  = (const float*)d_in[0];   // [32,64,64,64] fp32
    const float* cb = (const float*)d_in[1];   // [512,64] fp32

    float* cbn    = (float*)d_ws;              // 512*64 floats
    float* knorm2 = cbn + 512 * 64;            // 512 floats

    float* codes  = (float*)d_out;             // 32*64*64*64 floats
    float* idxout = codes + (size_t)32 * 64 * 64 * 64;  // 131072 floats (indices as f32)

    cb_norm_kernel<<<512, 64, 0, stream>>>(cb, cbn, knorm2);
    vq_kernel<<<512, 256, 0, stream>>>(x, cbn, knorm2, codes, idxout);
}

// Round 2
// 290.531 us; speedup vs baseline: 1.1863x; 1.1863x over previous
//
#include <hip/hip_runtime.h>

#define VQ_EPS 1e-12f

// Kernel 1: normalize codebook rows, store normalized rows + post-normalization
// squared norms (mirrors reference: sum(cb*cb) computed AFTER normalization).
__global__ __launch_bounds__(64) void cb_norm_kernel(const float* __restrict__ cb,
                                                     float* __restrict__ cbn,
                                                     float* __restrict__ knorm2) {
    const int k = blockIdx.x;       // 512 rows
    const int c = threadIdx.x;      // 64 channels
    float v = cb[k * 64 + c];
    float s = v * v;
    #pragma unroll
    for (int off = 32; off > 0; off >>= 1) s += __shfl_xor(s, off, 64);
    float n = sqrtf(s);
    float cn = v / fmaxf(n, VQ_EPS);     // elementwise divide, like F.normalize
    cbn[k * 64 + c] = cn;
    float s2 = cn * cn;
    #pragma unroll
    for (int off = 32; off > 0; off >>= 1) s2 += __shfl_xor(s2, off, 64);
    if (c == 0) knorm2[k] = s2;
}

// Kernel 2: one thread per pixel; lane = w -> coalesced x loads per channel and
// coalesced stores. x register-resident (float2[32], forced by launch_bounds
// VGPR cap of 256); codebook rows are wave-uniform -> scalar s_load path (free
// scalar pipe, SGPR operand feeds v_fmac directly). 4 independent FMA chains
// (d0.x,d0.y,d1.x,d1.y) cover the 4-cyc FMA latency at 2-cyc issue.
__global__ __launch_bounds__(256, 2) void vq_kernel(const float* __restrict__ x,
                                                    const float* __restrict__ cbn,
                                                    const float* __restrict__ knorm2,
                                                    float* __restrict__ codes,
                                                    float* __restrict__ idxout) {
    const int p = blockIdx.x * 256 + threadIdx.x;   // 131072 pixels
    const int w = p & 63;
    const int h = (p >> 6) & 63;
    const int b = p >> 12;

    const float* xp = x + ((size_t)b * 64 * 4096) + h * 64 + w;

    // Load the pixel's 64 channels into registers (strided 16 KB; coalesced
    // across lanes since lane = w).
    float2 xr[32];
    float ss = 0.0f;
    #pragma unroll
    for (int q = 0; q < 32; ++q) {
        float a0 = xp[(size_t)(2 * q) * 4096];
        float a1 = xp[(size_t)(2 * q + 1) * 4096];
        xr[q].x = a0;
        xr[q].y = a1;
        ss = fmaf(a0, a0, ss);
        ss = fmaf(a1, a1, ss);
    }
    const float inv = 1.0f / fmaxf(sqrtf(ss), VQ_EPS);  // IEEE divide (no fast-math)
    const float m2  = -2.0f * inv;   // score_k = knorm2[k] + m2 * (x_raw . cbn_k)

    float best = 3.0e38f;
    int bestk = 0;

    for (int k0 = 0; k0 < 512; k0 += 2) {
        const float2* r0 = (const float2*)(cbn + (size_t)k0 * 64);        // uniform addr -> s_load
        const float2* r1 = r0 + 32;
        float2 d0 = {0.0f, 0.0f};
        float2 d1 = {0.0f, 0.0f};
        #pragma unroll
        for (int q = 0; q < 32; ++q) {
            float2 a  = xr[q];
            float2 b0 = r0[q];
            float2 b1 = r1[q];
            d0.x = fmaf(a.x, b0.x, d0.x);
            d0.y = fmaf(a.y, b0.y, d0.y);
            d1.x = fmaf(a.x, b1.x, d1.x);
            d1.y = fmaf(a.y, b1.y, d1.y);
        }
        // score = ||cb_k||^2 - 2*inv*(x.cb_k); strict < keeps first-min (numpy tie-break)
        float s0 = fmaf(m2, d0.x + d0.y, knorm2[k0 + 0]);
        float s1 = fmaf(m2, d1.x + d1.y, knorm2[k0 + 1]);
        if (s0 < best) { best = s0; bestk = k0 + 0; }
        if (s1 < best) { best = s1; bestk = k0 + 1; }
    }

    // Epilogue: codes[b, :, h, w] = cbn[bestk, :]. Gather the winning row as
    // float4 (16 loads, L1/L2-hot 128 KB table), store per channel (coalesced
    // across lanes for each c).
    const float4* crow4 = (const float4*)(cbn + (size_t)bestk * 64);
    float* cp = codes + ((size_t)b * 64 * 4096) + h * 64 + w;
    #pragma unroll
    for (int q = 0; q < 16; ++q) {
        float4 v = crow4[q];
        cp[(size_t)(4 * q + 0) * 4096] = v.x;
        cp[(size_t)(4 * q + 1) * 4096] = v.y;
        cp[(size_t)(4 * q + 2) * 4096] = v.z;
        cp[(size_t)(4 * q + 3) * 4096] = v.w;
    }
    idxout[(b * 64 + h) * 64 + w] = (float)bestk;
}

extern "C" void kernel_launch(void* const* d_in, const int* in_sizes, int n_in,
                              void* d_out, int out_size, void* d_ws, size_t ws_size,
                              hipStream_t stream) {
    const float* x  = (const float*)d_in[0];   // [32,64,64,64] fp32
    const float* cb = (const float*)d_in[1];   // [512,64] fp32

    float* cbn    = (float*)d_ws;              // 512*64 floats
    float* knorm2 = cbn + 512 * 64;            // 512 floats

    float* codes  = (float*)d_out;             // 32*64*64*64 floats
    float* idxout = codes + (size_t)32 * 64 * 64 * 64;  // 131072 floats (indices as f32)

    cb_norm_kernel<<<512, 64, 0, stream>>>(cb, cbn, knorm2);
    vq_kernel<<<512, 256, 0, stream>>>(x, cbn, knorm2, codes, idxout);
}

// Round 3
// 248.629 us; speedup vs baseline: 1.3863x; 1.1685x over previous
//
#include <hip/hip_runtime.h>

#define VQ_EPS 1e-12f

typedef float v2f __attribute__((ext_vector_type(2)));

static __device__ __forceinline__ v2f vfma2(v2f a, v2f b, v2f c) {
#if __has_builtin(__builtin_elementwise_fma)
    return __builtin_elementwise_fma(a, b, c);   // -> llvm.fma.v2f32 -> v_pk_fma_f32
#else
    v2f r; r.x = fmaf(a.x, b.x, c.x); r.y = fmaf(a.y, b.y, c.y); return r;
#endif
}

// Kernel 1: normalize codebook rows. Outputs:
//   cbn   [512][64] row-major  (epilogue gather of the winning row)
//   cbT   [64][512] chan-major (main loop: 64 contiguous wave-uniform floats
//                               per (tile, channel) -> s_load_dwordx16 path)
//   knorm2[512]                (sum(cbn^2) AFTER normalization, like reference)
__global__ __launch_bounds__(64) void cb_norm_kernel(const float* __restrict__ cb,
                                                     float* __restrict__ cbn,
                                                     float* __restrict__ cbT,
                                                     float* __restrict__ knorm2) {
    const int k = blockIdx.x;       // 512 rows
    const int c = threadIdx.x;      // 64 channels
    float v = cb[k * 64 + c];
    float s = v * v;
    #pragma unroll
    for (int off = 32; off > 0; off >>= 1) s += __shfl_xor(s, off, 64);
    float n = sqrtf(s);
    float cn = v / fmaxf(n, VQ_EPS);     // elementwise divide, like F.normalize
    cbn[k * 64 + c] = cn;
    cbT[c * 512 + k] = cn;
    float s2 = cn * cn;
    #pragma unroll
    for (int off = 32; off > 0; off >>= 1) s2 += __shfl_xor(s2, off, 64);
    if (c == 0) knorm2[k] = s2;
}

// Kernel 2: one thread per pixel; lane = w -> coalesced x loads/stores.
// K tiled by 64: accumulators (loop-carried, unsinkable) own 64 VGPRs;
// x is STREAMED one channel at a time (8 re-reads total, L1/L2-absorbed).
// Codebook comes in via wave-uniform scalar loads from cbT; consecutive
// codes sit in adjacent SGPRs so the FMA packs to v_pk_fma_f32.
__global__ __launch_bounds__(256) void vq_kernel(const float* __restrict__ x,
                                                 const float* __restrict__ cbn,
                                                 const float* __restrict__ cbT,
                                                 const float* __restrict__ knorm2,
                                                 float* __restrict__ codes,
                                                 float* __restrict__ idxout) {
    const int p = blockIdx.x * 256 + threadIdx.x;   // 131072 pixels
    const int w = p & 63;
    const int h = (p >> 6) & 63;
    const int b = p >> 12;

    const float* xp = x + ((size_t)b * 64 * 4096) + h * 64 + w;

    // ||x_raw||: one streaming pass (also warms L1/L2 for the tiles).
    float ss = 0.0f;
    #pragma unroll 8
    for (int c = 0; c < 64; ++c) {
        float a = xp[(size_t)c * 4096];
        ss = fmaf(a, a, ss);
    }
    const float inv = 1.0f / fmaxf(sqrtf(ss), VQ_EPS);  // IEEE divide (no fast-math)
    const float m2  = -2.0f * inv;   // score_k = knorm2[k] + m2 * (x_raw . cbn_k)

    float best = 3.0e38f;
    int bestk = 0;

    for (int t = 0; t < 8; ++t) {
        const int kbase = t * 64;

        v2f acc[32];
        #pragma unroll
        for (int i = 0; i < 32; ++i) acc[i] = (v2f){0.0f, 0.0f};

        #pragma unroll 2
        for (int c = 0; c < 64; ++c) {
            float xc = xp[(size_t)c * 4096];                 // vector load, L1/L2-hot
            v2f xc2 = {xc, xc};
            const v2f* cbc = (const v2f*)(cbT + (size_t)c * 512 + kbase); // uniform -> s_load
            #pragma unroll
            for (int i = 0; i < 32; ++i)
                acc[i] = vfma2(xc2, cbc[i], acc[i]);
        }

        // score = ||cb_k||^2 - 2*inv*(x.cb_k); ascending k + strict < keeps
        // the first minimum (numpy argmin tie-break).
        const float* kn = knorm2 + kbase;                    // uniform -> s_load
        #pragma unroll
        for (int i = 0; i < 32; ++i) {
            float s0 = fmaf(m2, acc[i].x, kn[2 * i + 0]);
            float s1 = fmaf(m2, acc[i].y, kn[2 * i + 1]);
            if (s0 < best) { best = s0; bestk = kbase + 2 * i + 0; }
            if (s1 < best) { best = s1; bestk = kbase + 2 * i + 1; }
        }
    }

    // Epilogue: codes[b, :, h, w] = cbn[bestk, :] (divergent float4 gathers from
    // the L2-hot 128 KB table; stores coalesced across lanes per channel).
    const float4* crow4 = (const float4*)(cbn + (size_t)bestk * 64);
    float* cp = codes + ((size_t)b * 64 * 4096) + h * 64 + w;
    #pragma unroll
    for (int q = 0; q < 16; ++q) {
        float4 v = crow4[q];
        cp[(size_t)(4 * q + 0) * 4096] = v.x;
        cp[(size_t)(4 * q + 1) * 4096] = v.y;
        cp[(size_t)(4 * q + 2) * 4096] = v.z;
        cp[(size_t)(4 * q + 3) * 4096] = v.w;
    }
    idxout[(b * 64 + h) * 64 + w] = (float)bestk;
}

extern "C" void kernel_launch(void* const* d_in, const int* in_sizes, int n_in,
                              void* d_out, int out_size, void* d_ws, size_t ws_size,
                              hipStream_t stream) {
    const float* x  = (const float*)d_in[0];   // [32,64,64,64] fp32
    const float* cb = (const float*)d_in[1];   // [512,64] fp32

    float* cbn    = (float*)d_ws;              // 512*64 floats
    float* cbT    = cbn + 512 * 64;            // 64*512 floats (transposed)
    float* knorm2 = cbT + 512 * 64;            // 512 floats

    float* codes  = (float*)d_out;             // 32*64*64*64 floats
    float* idxout = codes + (size_t)32 * 64 * 64 * 64;  // 131072 floats (indices as f32)

    cb_norm_kernel<<<512, 64, 0, stream>>>(cb, cbn, cbT, knorm2);
    vq_kernel<<<512, 256, 0, stream>>>(x, cbn, cbT, knorm2, codes, idxout);
}